// Round 7
// baseline (252.906 us; speedup 1.0000x reference)
//
#include <hip/hip_runtime.h>
#include <math.h>

// Problem constants
#define B_ROWS 16384      // 8*2048 batch rows
#define IDIM   1024
#define ODIM   1024
#define NGRID  9          // NUM_SEGMENTS + 1

#define RS_BLOCKS 1024
#define RS_ROWS   (B_ROWS / RS_BLOCKS)   // 16 rows per block

// GEMM: BM=256 rows, BN=128 real cols (x2 planes -> 256 eff), BK=64, 8 waves,
// m201 8-phase schedule with ONE counted vmcnt(6) per K-tile.
// m-slots: max sum over buckets of ceil(cnt/256) <= 64 + 9 = 73 -> 80.
#define GEMM_MSLOTS 80
#define GEMM_NT     8
#define GEMM_BLOCKS (GEMM_MSLOTS * GEMM_NT)   // 640

typedef __attribute__((ext_vector_type(8))) short frag8;   // 8 x bf16 (4 VGPRs)
typedef __attribute__((ext_vector_type(4))) float f32x4;   // MFMA accumulator

typedef __attribute__((address_space(1))) void gvoid;
typedef __attribute__((address_space(3))) void lvoid;

__device__ __forceinline__ void async_cp16(const void* g, void* l) {
  // 16B/lane global->LDS DMA; LDS dest = wave-uniform base + lane*16.
  __builtin_amdgcn_global_load_lds((gvoid*)(void*)g, (lvoid*)l, 16, 0, 0);
}

__device__ __forceinline__ unsigned short f2bf(float f) {
  union { float f; unsigned u; } v; v.f = f;
  unsigned u = v.u;
  u += 0x7fffu + ((u >> 16) & 1u);      // round-to-nearest-even
  return (unsigned short)(u >> 16);
}

// Per-row hat weights: at most 2 nonzero, at segments {s, s+1}
__device__ __forceinline__ void seg_weights(float m, int& sI, float& w0, float& w1) {
  float wsum = 0.f, wg[NGRID];
#pragma unroll
  for (int g = 0; g < NGRID; g++) {
    float gv = -1.f + 0.25f * (float)g;
    float t = 1.f - fabsf(m - gv) * 4.f;   // 1/h = 4
    wg[g] = t > 0.f ? t : 0.f;
    wsum += wg[g];
  }
  int s = (int)floorf((m + 1.f) * 4.f);
  s = s < 0 ? 0 : (s > 7 ? 7 : s);
  float inv = 1.f / (wsum + 1e-8f);
  sI = s;
  w0 = wg[s] * inv;
  w1 = wg[s + 1] * inv;
}

// ---------------- Pass 1 (fused): mean/weights/segment + bf16 cvt + seg lists --
__global__ void row_stats_fused(const float* __restrict__ x,
                                unsigned short* __restrict__ Xb,
                                float2* __restrict__ ws_s,
                                int* __restrict__ seg_rows,
                                int* __restrict__ bucket_cnt) {
  __shared__ int lcnt[NGRID];
  __shared__ int base[NGRID];
  __shared__ int lrank[RS_ROWS];
  __shared__ int lseg[RS_ROWS];
  __shared__ float2 lws[RS_ROWS];
  const int tid  = threadIdx.x;          // 256 threads, 4 waves
  const int lane = tid & 63;
  const int wave = tid >> 6;
  if (tid < NGRID) lcnt[tid] = 0;
  __syncthreads();
  const int row0 = blockIdx.x * RS_ROWS;
#pragma unroll
  for (int it = 0; it < RS_ROWS / 4; ++it) {
    int r = it * 4 + wave;               // one wave per row
    int b = row0 + r;
    const float4* xr = (const float4*)(x + (size_t)b * IDIM);
    ushort4* xw = (ushort4*)(Xb + (size_t)b * IDIM);
    float4 v[4];
    float s = 0.f;
#pragma unroll
    for (int j = 0; j < 4; j++) {        // 4 independent 16B loads/lane
      v[j] = xr[lane + j * 64];
      s += v[j].x + v[j].y + v[j].z + v[j].w;
    }
#pragma unroll
    for (int j = 0; j < 4; j++) {        // bf16 copy straight from registers
      ushort4 u;
      u.x = f2bf(v[j].x); u.y = f2bf(v[j].y); u.z = f2bf(v[j].z); u.w = f2bf(v[j].w);
      xw[lane + j * 64] = u;
    }
#pragma unroll
    for (int off = 32; off; off >>= 1) s += __shfl_down(s, off, 64);
    if (lane == 0) {
      float m = s * (1.0f / (float)IDIM);
      int sI; float w0, w1;
      seg_weights(m, sI, w0, w1);
      lws[r] = make_float2(w0, w1);
      lseg[r] = sI;
      lrank[r] = atomicAdd(&lcnt[sI], 1);   // LDS atomic: cheap
    }
  }
  __syncthreads();
  if (tid < NGRID) base[tid] = lcnt[tid] ? atomicAdd(&bucket_cnt[tid], lcnt[tid]) : 0;
  __syncthreads();
  if (tid < RS_ROWS) {
    int p = lseg[tid] * B_ROWS + base[lseg[tid]] + lrank[tid];
    seg_rows[p] = row0 + tid;
    ws_s[p] = lws[tid];
  }
}

// ---------------- Pass 2: coeff fp32 -> bf16, only planes actually needed ----
#define CV_BLKS_PER_PLANE (ODIM * IDIM / 4 / 256)   // 1024
__global__ void cvt_coeff(const float* __restrict__ c, unsigned short* __restrict__ cb,
                          const int* __restrict__ bucket_cnt) {
  const int g  = blockIdx.x >> 10;            // plane 0..8
  const int cI = blockIdx.x & 1023;
  bool need = bucket_cnt[g] > 0;
  if (!need && g > 0) need = bucket_cnt[g - 1] > 0;
  if (!need) return;
  int i = (g * CV_BLKS_PER_PLANE + cI) * 256 + threadIdx.x;
  float4 v = ((const float4*)c)[i];
  ushort4 o;
  o.x = f2bf(v.x); o.y = f2bf(v.y); o.z = f2bf(v.z); o.w = f2bf(v.w);
  ((ushort4*)cb)[i] = o;
}

// ---------------- Pass 3: MFMA GEMM, 256x256eff, 8-phase counted-vmcnt -------
// acc[p] = X[rows] @ coeff[seg+p]^T (K=1024); out = w0*acc0 + w1*acc1 + bias.
// 8 waves (2M x 4N): wave output 128 rows x 64 eff cols. LDS 128 KB (2 dbuf x
// (A 32KB + B 32KB)). Half-tile = 128 rows x 64 k (16 KB = 2 issues/wave).
// Stage stream (7 halves ahead): prologue T0.{A0,B0,A1,B1},T1.{A0,B0,A1};
// then p1:T+1.B1, p2:T+2.A0, p3:T+2.B0, p4:T+2.A1 (per half-cycle).
// ONE vmcnt(6) per K-tile (end of p4/p8): retires everything but the newest
// 3 halves -> next tile fully in LDS; 3 halves (~48KB) stay in flight across
// barriers. WAR-safe: each staged half's region had its last ds_read retired
// by that phase's opening lgkmcnt(0) + closing barrier, >=1 barrier earlier.
// Tail: prefetch tile index clamped to 15 (re-stages identical resident
// bytes, or dead regions) -- keeps vmcnt counts uniform, no scratch target.
// Layout/swizzle = R6's measured-zero-conflict scheme: rows of 64 shorts
// (128B); 16B chunk d of row r stored at slot d^(r&7); staging lane l
// (row l>>3, slot l&7) reads source chunk (l&7)^(l>>3); reader chunk
// kh*4+(lane>>4) at slot ^(lane&7) -> 2 lanes/bank-quad = free [m136].
__global__ void __launch_bounds__(512, 2)
kan_gemm(const unsigned short* __restrict__ Xb,
         const unsigned short* __restrict__ Cb,
         const int* __restrict__ seg_rows,
         const int* __restrict__ bucket_cnt,
         const float2* __restrict__ ws_s,
         const float* __restrict__ bias,
         float* __restrict__ out) {
  // XCD swizzle: sub&7 -> m-class (same XCD via round-robin), sub>>3 -> n-tile.
  const int sub = blockIdx.x & 63;
  const int mt  = (blockIdx.x >> 6) * 8 + (sub & 7);
  const int nt  = sub >> 3;                 // 0..7 (128 real cols each)

  int seg = -1, lt = 0, cnt = 0;
  {
    int t0 = 0;
#pragma unroll
    for (int g = 0; g < NGRID; g++) {
      int c   = bucket_cnt[g];
      int ntg = (c + 255) >> 8;
      if (mt >= t0 && mt < t0 + ntg) { seg = g; lt = mt - t0; cnt = c; }
      t0 += ntg;
    }
  }
  if (seg < 0) return;                      // uniform over block: barrier-safe
  const int rlim = cnt - lt * 256;          // valid rows in this tile (1..256)
  const int* rows = seg_rows + seg * B_ROWS + lt * 256;

  __shared__ unsigned short As[2][256 * 64];   // 2 x 32 KB
  __shared__ unsigned short Bs[2][256 * 64];   // 2 x 32 KB

  const int tid  = threadIdx.x;
  const int lane = tid & 63;
  const int wave = tid >> 6;                // 0..7
  const int wm   = wave >> 2;               // 0..1
  const int wn   = wave & 3;                // 0..3
  const int colB0 = nt * 128;

  // ---- staging geometry: issue = 8 rows x 128B; wave covers 16 rows/half ----
  const int srow = lane >> 3;                   // 0..7 row within issue
  const int sOff = ((lane & 7) ^ srow) * 8;     // swizzled src chunk (shorts)

  const unsigned short* gA[2][2];
  const unsigned short* gB[2][2];
#pragma unroll
  for (int h = 0; h < 2; h++)
#pragma unroll
    for (int i = 0; i < 2; i++) {
      int idx = h * 128 + wave * 16 + i * 8 + srow;
      int rid = rows[idx < rlim ? idx : rlim - 1];
      gA[h][i] = Xb + (size_t)rid * IDIM + sOff;
      int realcol = wave * 16 + i * 8 + srow;   // B half h = plane h
      gB[h][i] = Cb + ((size_t)((seg + h) * ODIM + colB0 + realcol)) * IDIM + sOff;
    }

  // ---- reader geometry (R6-proven): chunk kh*4+(lane>>4), slot ^(lane&7) ----
  const int rsw0 = ((0 + ((lane >> 4) & 3)) ^ (lane & 7)) * 8;   // kh=0
  const int rsw1 = ((4 + ((lane >> 4) & 3)) ^ (lane & 7)) * 8;   // kh=1

  f32x4 acc[8][4] = {};    // [mi][NH*2+ni']; mi = MH*4+mi'
  frag8 af[8];             // current MH: [mi'*2 + kh]
  frag8 bf[8];             // all 4 ni:   [(NH*2+ni')*2 + kh]

#define STAGE_A(BUF, T, H) do {                                                \
    const int tt_ = (T) > 15 ? 15 : (T);                                       \
    _Pragma("unroll")                                                          \
    for (int i_ = 0; i_ < 2; i_++)                                             \
      async_cp16(gA[H][i_] + tt_ * 64,                                         \
                 &As[BUF][((H) * 128 + wave * 16 + i_ * 8) * 64]);             \
    __builtin_amdgcn_sched_barrier(0);                                         \
  } while (0)

#define STAGE_B(BUF, T, H) do {                                                \
    const int tt_ = (T) > 15 ? 15 : (T);                                       \
    _Pragma("unroll")                                                          \
    for (int i_ = 0; i_ < 2; i_++)                                             \
      async_cp16(gB[H][i_] + tt_ * 64,                                         \
                 &Bs[BUF][((H) * 128 + wave * 16 + i_ * 8) * 64]);             \
    __builtin_amdgcn_sched_barrier(0);                                         \
  } while (0)

#define LOAD_AF(BUF, MH) do {                                                  \
    _Pragma("unroll")                                                          \
    for (int mi_ = 0; mi_ < 4; mi_++) {                                        \
      const int r_ = ((MH) * 128 + wm * 64 + mi_ * 16 + (lane & 15)) * 64;     \
      af[mi_ * 2 + 0] = *(const frag8*)&As[BUF][r_ + rsw0];                    \
      af[mi_ * 2 + 1] = *(const frag8*)&As[BUF][r_ + rsw1];                    \
    }                                                                          \
  } while (0)

#define LOAD_BF(BUF, NH) do {                                                  \
    _Pragma("unroll")                                                          \
    for (int ni_ = 0; ni_ < 2; ni_++) {                                        \
      const int r_ = ((NH) * 128 + wn * 32 + ni_ * 16 + (lane & 15)) * 64;     \
      bf[((NH) * 2 + ni_) * 2 + 0] = *(const frag8*)&Bs[BUF][r_ + rsw0];       \
      bf[((NH) * 2 + ni_) * 2 + 1] = *(const frag8*)&Bs[BUF][r_ + rsw1];       \
    }                                                                          \
  } while (0)

#define MFMA_Q(MH, NH) do {                                                    \
    __builtin_amdgcn_s_setprio(1);                                             \
    _Pragma("unroll")                                                          \
    for (int mi_ = 0; mi_ < 4; mi_++)                                          \
      _Pragma("unroll")                                                        \
      for (int ni_ = 0; ni_ < 2; ni_++)                                        \
        _Pragma("unroll")                                                      \
        for (int kh_ = 0; kh_ < 2; kh_++)                                      \
          acc[(MH) * 4 + mi_][(NH) * 2 + ni_] =                                \
              __builtin_amdgcn_mfma_f32_16x16x32_bf16(                         \
                  af[mi_ * 2 + kh_], bf[((NH) * 2 + ni_) * 2 + kh_],           \
                  acc[(MH) * 4 + mi_][(NH) * 2 + ni_], 0, 0, 0);               \
    __builtin_amdgcn_s_setprio(0);                                             \
  } while (0)

#define BAR   __builtin_amdgcn_s_barrier()
#define LGKM0 do { asm volatile("s_waitcnt lgkmcnt(0)" ::: "memory");          \
                   __builtin_amdgcn_sched_barrier(0); } while (0)
#define VM6   do { asm volatile("s_waitcnt vmcnt(6)" ::: "memory");            \
                   __builtin_amdgcn_sched_barrier(0); } while (0)

  // ---- prologue: 7 halves in exact stream order (14 loads/wave) ----
  STAGE_A(0, 0, 0);   // T0.A0
  STAGE_B(0, 0, 0);   // T0.B0
  STAGE_A(0, 0, 1);   // T0.A1
  STAGE_B(0, 0, 1);   // T0.B1
  STAGE_A(1, 1, 0);   // T1.A0
  STAGE_B(1, 1, 0);   // T1.B0
  STAGE_A(1, 1, 1);   // T1.A1
  VM6;                // T0's 4 halves landed (per-wave); BAR => block-wide
  BAR;

  for (int t = 0; t < 16; t += 2) {
    // ================= half-cycle A: tile t from buf0 =================
    // p1: read A0+B0; stage (t+1).B1 -> buf1
    LOAD_AF(0, 0); LOAD_BF(0, 0);
    STAGE_B(1, t + 1, 1);
    BAR; LGKM0;
    MFMA_Q(0, 0);
    BAR;
    // p2: read B1; stage (t+2).A0 -> buf0 (A0 last read p1)
    LOAD_BF(0, 1);
    STAGE_A(0, t + 2, 0);
    BAR; LGKM0;
    MFMA_Q(0, 1);
    BAR;
    // p3: read A1; stage (t+2).B0 -> buf0 (B0 last read p1)
    LOAD_AF(0, 1);
    STAGE_B(0, t + 2, 0);
    BAR; LGKM0;
    MFMA_Q(1, 1);
    BAR;
    // p4: stage (t+2).A1 -> buf0 (A1 last read p3); vmcnt gate for tile t+1
    STAGE_A(0, t + 2, 1);
    BAR;
    MFMA_Q(1, 0);
    VM6;
    BAR;
    // ================= half-cycle B: tile t+1 from buf1 =================
    // p5: read A0+B0; stage (t+2).B1 -> buf0 (B1 last read p2)
    LOAD_AF(1, 0); LOAD_BF(1, 0);
    STAGE_B(0, t + 2, 1);
    BAR; LGKM0;
    MFMA_Q(0, 0);
    BAR;
    // p6: read B1; stage (t+3).A0 -> buf1 (A0 last read p5)
    LOAD_BF(1, 1);
    STAGE_A(1, t + 3, 0);
    BAR; LGKM0;
    MFMA_Q(0, 1);
    BAR;
    // p7: read A1; stage (t+3).B0 -> buf1 (B0 last read p5)
    LOAD_AF(1, 1);
    STAGE_B(1, t + 3, 0);
    BAR; LGKM0;
    MFMA_Q(1, 1);
    BAR;
    // p8: stage (t+3).A1 -> buf1 (A1 last read p7); vmcnt gate for tile t+2
    STAGE_A(1, t + 3, 1);
    BAR;
    MFMA_Q(1, 0);
    VM6;
    BAR;
  }
#undef STAGE_A
#undef STAGE_B
#undef LOAD_AF
#undef LOAD_BF
#undef MFMA_Q
#undef BAR
#undef LGKM0
#undef VM6

  // ---- epilogue: D col = lane&15, row = (lane>>4)*4 + reg [m89/m91 verified] --
  const float2* wss = ws_s + seg * B_ROWS + lt * 256;
  int   col[2]; float bv[2];
#pragma unroll
  for (int nc = 0; nc < 2; nc++) {
    col[nc] = colB0 + wn * 32 + nc * 16 + (lane & 15);
    bv[nc]  = bias[col[nc]];
  }
#pragma unroll
  for (int mi = 0; mi < 8; mi++) {
    int irow = (mi >> 2) * 128 + wm * 64 + (mi & 3) * 16 + (lane >> 4) * 4;
#pragma unroll
    for (int r = 0; r < 4; r++) {
      int idx = irow + r;
      if (idx < rlim) {                     // non-padding row
        int orow = rows[idx];
        float2 w = wss[idx];
        float* o = out + (size_t)orow * ODIM;
#pragma unroll
        for (int nc = 0; nc < 2; nc++)
          o[col[nc]] = w.x * acc[mi][nc][r] + w.y * acc[mi][2 + nc][r] + bv[nc];
      }
    }
  }
}

// ---------------- Fallback (ws too small): slow fp32, correct ----------------
__global__ void fallback_kernel(const float* __restrict__ x, const float* __restrict__ coeff,
                                const float* __restrict__ bias, float* __restrict__ out) {
  int b = blockIdx.x;
  int tid = threadIdx.x;
  __shared__ float xs[IDIM];
  __shared__ float ps[4];
  __shared__ float mw[2];
  __shared__ int   ms;
  float4 v = ((const float4*)(x + (size_t)b * IDIM))[tid];
  ((float4*)xs)[tid] = v;
  float s = v.x + v.y + v.z + v.w;
#pragma unroll
  for (int off = 32; off; off >>= 1) s += __shfl_down(s, off, 64);
  if ((tid & 63) == 0) ps[tid >> 6] = s;
  __syncthreads();
  if (tid == 0) {
    float m = (ps[0] + ps[1] + ps[2] + ps[3]) * (1.0f / (float)IDIM);
    int sI; float w0, w1;
    seg_weights(m, sI, w0, w1);
    mw[0] = w0; mw[1] = w1; ms = sI;
  }
  __syncthreads();
  float w0 = mw[0], w1 = mw[1]; int sI = ms;
  for (int o = tid; o < ODIM; o += 256) {
    const float* c0 = coeff + ((size_t)sI * ODIM + o) * IDIM;
    const float* c1 = c0 + (size_t)ODIM * IDIM;
    float a0 = 0.f, a1 = 0.f;
    for (int i = 0; i < IDIM; i++) { a0 += xs[i] * c0[i]; a1 += xs[i] * c1[i]; }
    out[(size_t)b * ODIM + o] = w0 * a0 + w1 * a1 + bias[o];
  }
}

extern "C" void kernel_launch(void* const* d_in, const int* in_sizes, int n_in,
                              void* d_out, int out_size, void* d_ws, size_t ws_size,
                              hipStream_t stream) {
  const float* x     = (const float*)d_in[0];
  const float* coeff = (const float*)d_in[1];
  const float* bias  = (const float*)d_in[2];
  float* out = (float*)d_out;

  // Workspace layout (16B-aligned chunks)
  size_t szXb = (size_t)B_ROWS * IDIM * sizeof(unsigned short);       // 33,554,432
  size_t szCb = (size_t)NGRID * ODIM * IDIM * sizeof(unsigned short); // 18,874,368
  size_t o0 = 0;
  unsigned short* Xb = (unsigned short*)((char*)d_ws + o0); o0 += szXb;
  unsigned short* Cb = (unsigned short*)((char*)d_ws + o0); o0 += szCb;
  float2* ws_s = (float2*)((char*)d_ws + o0); o0 += (size_t)NGRID * B_ROWS * 8;
  int* seg_rows = (int*)((char*)d_ws + o0); o0 += (size_t)NGRID * B_ROWS * 4;
  int* bucket_cnt = (int*)((char*)d_ws + o0); o0 += 256;

  if (ws_size < o0) {
    // Emergency slow path: no workspace required.
    fallback_kernel<<<B_ROWS, 256, 0, stream>>>(x, coeff, bias, out);
    return;
  }

  hipMemsetAsync(bucket_cnt, 0, NGRID * sizeof(int), stream);
  row_stats_fused<<<RS_BLOCKS, 256, 0, stream>>>(x, Xb, ws_s, seg_rows, bucket_cnt);
  cvt_coeff<<<NGRID * CV_BLKS_PER_PLANE, 256, 0, stream>>>(coeff, Cb, bucket_cnt);
  kan_gemm<<<GEMM_BLOCKS, 512, 0, stream>>>(Xb, Cb, seg_rows, bucket_cnt, ws_s, bias, out);
}